// Round 1
// baseline (341.213 us; speedup 1.0000x reference)
//
#include <hip/hip_runtime.h>
#include <hip/hip_bf16.h>
#include <cstdint>

#define EMBED 256
#define GPS 8        // groups
#define NCAM 6
#define NLVL 4
#define NPT 13
#define NANC 900
#define NSAMP (NCAM*NLVL*NPT)   // 312
#define NWCOL (GPS*NSAMP)       // 2496

__device__ __forceinline__ float4 ld_bf16x4(const __hip_bfloat16* p) {
    const ushort4 u = *reinterpret_cast<const ushort4*>(p);
    float4 f;
    f.x = __uint_as_float(((unsigned)u.x) << 16);
    f.y = __uint_as_float(((unsigned)u.y) << 16);
    f.z = __uint_as_float(((unsigned)u.z) << 16);
    f.w = __uint_as_float(((unsigned)u.w) << 16);
    return f;
}

__device__ __forceinline__ void fma4(float4& a, float s, const float4& w) {
    a.x = fmaf(s, w.x, a.x); a.y = fmaf(s, w.y, a.y);
    a.z = fmaf(s, w.z, a.z); a.w = fmaf(s, w.w, a.w);
}

// ---------------- K1: transpose (c,E,HW) f32 -> (c,HW,E) bf16 ----------------
// thread t = channel e; per-thread sequential reads along hw (L1-friendly),
// writes coalesced across lanes (e contiguous).
__global__ __launch_bounds__(256) void k_transpose(const float* __restrict__ in,
                                                   __hip_bfloat16* __restrict__ out,
                                                   int HW, int chunks) {
    int b = blockIdx.x;
    int c = b / chunks;
    int hw0 = (b - c * chunks) * 64;
    int e = threadIdx.x;
    const float* src = in + ((size_t)c * EMBED + e) * HW;
    __hip_bfloat16* dst = out + (size_t)c * HW * EMBED + e;
    #pragma unroll
    for (int i = 0; i < 64; i += 4) {
        int hw = hw0 + i;
        if (hw < HW) {
            float4 v = *reinterpret_cast<const float4*>(src + hw);
            dst[(size_t)(hw + 0) * EMBED] = __float2bfloat16(v.x);
            dst[(size_t)(hw + 1) * EMBED] = __float2bfloat16(v.y);
            dst[(size_t)(hw + 2) * EMBED] = __float2bfloat16(v.z);
            dst[(size_t)(hw + 3) * EMBED] = __float2bfloat16(v.w);
        }
    }
}

// ---------------- K2a: logits = (inst+anchor) @ w_weights + b ----------------
// grid (90, 3): 10 anchors x 832 cols per block; thread owns a 4-col quad,
// register-tiles 10 anchors (feat row in LDS, broadcast reads).
#define ATILE 10
#define JT 832
__global__ __launch_bounds__(256) void k_logits(const float* __restrict__ inst,
                                                const float* __restrict__ anch,
                                                const float* __restrict__ wlin,
                                                const float* __restrict__ blin,
                                                float* __restrict__ logits) {
    __shared__ float fS[ATILE][EMBED];
    int a0 = blockIdx.x * ATILE;
    for (int idx = threadIdx.x; idx < ATILE * EMBED; idx += 256)
        ((float*)fS)[idx] = inst[(size_t)a0 * EMBED + idx] + anch[(size_t)a0 * EMBED + idx];
    __syncthreads();
    int q = threadIdx.x;
    if (q >= JT / 4) return;
    int col = blockIdx.y * JT + q * 4;
    float4 acc[ATILE];
    #pragma unroll
    for (int t = 0; t < ATILE; t++) acc[t] = make_float4(0.f, 0.f, 0.f, 0.f);
    for (int k = 0; k < EMBED; k += 4) {
        float4 w0 = *(const float4*)&wlin[(size_t)(k + 0) * NWCOL + col];
        float4 w1 = *(const float4*)&wlin[(size_t)(k + 1) * NWCOL + col];
        float4 w2 = *(const float4*)&wlin[(size_t)(k + 2) * NWCOL + col];
        float4 w3 = *(const float4*)&wlin[(size_t)(k + 3) * NWCOL + col];
        #pragma unroll
        for (int t = 0; t < ATILE; t++) {
            float4 f = *(const float4*)&fS[t][k];
            fma4(acc[t], f.x, w0); fma4(acc[t], f.y, w1);
            fma4(acc[t], f.z, w2); fma4(acc[t], f.w, w3);
        }
    }
    float4 bv = *(const float4*)&blin[col];
    #pragma unroll
    for (int t = 0; t < ATILE; t++) {
        float4 r;
        r.x = acc[t].x + bv.x; r.y = acc[t].y + bv.y;
        r.z = acc[t].z + bv.z; r.w = acc[t].w + bv.w;
        *(float4*)&logits[(size_t)(a0 + t) * NWCOL + col] = r;
    }
}

// ---------------- K2b: softmax over 312 samples per (anchor, group), in-place -
__global__ __launch_bounds__(256) void k_softmax(float* __restrict__ w) {
    __shared__ float l[NWCOL];
    __shared__ float gmax[GPS], grs[GPS];
    int a = blockIdx.x;
    for (int j = threadIdx.x; j < NWCOL; j += 256) l[j] = w[(size_t)a * NWCOL + j];
    __syncthreads();
    int g = threadIdx.x >> 5;     // 8 teams of 32 lanes
    int i = threadIdx.x & 31;
    float m = -1e30f;
    for (int s = i; s < NSAMP; s += 32) m = fmaxf(m, l[s * GPS + g]);
    #pragma unroll
    for (int off = 16; off; off >>= 1) m = fmaxf(m, __shfl_xor(m, off, 32));
    float ssum = 0.f;
    for (int s = i; s < NSAMP; s += 32) ssum += __expf(l[s * GPS + g] - m);
    #pragma unroll
    for (int off = 16; off; off >>= 1) ssum += __shfl_xor(ssum, off, 32);
    if (i == 0) { gmax[g] = m; grs[g] = 1.f / ssum; }
    __syncthreads();
    for (int j = threadIdx.x; j < NWCOL; j += 256) {
        int gg = j & 7;
        w[(size_t)a * NWCOL + j] = __expf(l[j] - gmax[gg]) * grs[gg];
    }
}

// ---------------- K2c: project key points to per-camera pixel coords ---------
__global__ __launch_bounds__(256) void k_project(const float* __restrict__ kp,
                                                 const float* __restrict__ proj,
                                                 float* __restrict__ pxy) {
    int t = blockIdx.x * 256 + threadIdx.x;
    if (t >= NANC * NCAM * NPT) return;
    int a = t / (NCAM * NPT);
    int r = t - a * (NCAM * NPT);
    int c = r / NPT;
    int p = r - c * NPT;
    const float* M = proj + c * 16;
    const float* k3 = kp + ((size_t)a * NPT + p) * 3;
    float kx = k3[0], ky = k3[1], kz = k3[2];
    float X = M[0] * kx + M[1] * ky + M[2] * kz + M[3];
    float Y = M[4] * kx + M[5] * ky + M[6] * kz + M[7];
    float Z = M[8] * kx + M[9] * ky + M[10] * kz + M[11];
    float invz = 1.f / fmaxf(Z, 1e-5f);
    pxy[(size_t)t * 2 + 0] = X * invz;   // pixel x (pre level scaling)
    pxy[(size_t)t * 2 + 1] = Y * invz;   // pixel y
}

// ---------------- K3: bilinear gather + weighted fusion ----------------------
// block = 1 anchor, 4 waves; lanes = 64 channel-quads (e0 = lane*4);
// waves split the 78 (cam,pt) pairs per level; fully-outside samples are a
// wave-uniform skip (no loads, no FMAs).
__global__ __launch_bounds__(256) void k_aggregate(const __hip_bfloat16* __restrict__ f0,
                                                   const __hip_bfloat16* __restrict__ f1,
                                                   const __hip_bfloat16* __restrict__ f2,
                                                   const __hip_bfloat16* __restrict__ f3,
                                                   const float* __restrict__ w,
                                                   const float* __restrict__ pxy,
                                                   float* __restrict__ fused) {
    __shared__ float wS[NWCOL];            // 9984 B
    __shared__ float xyS[NCAM * NPT * 2];  // 624 B
    __shared__ float redS[4][EMBED];       // 4 KB
    int a = blockIdx.x;
    for (int j = threadIdx.x; j < NWCOL; j += 256) wS[j] = w[(size_t)a * NWCOL + j];
    for (int j = threadIdx.x; j < NCAM * NPT * 2; j += 256)
        xyS[j] = pxy[(size_t)a * NCAM * NPT * 2 + j];
    __syncthreads();
    int wave = threadIdx.x >> 6;
    int lane = threadIdx.x & 63;
    int e0 = lane * 4;
    int g = lane >> 3;
    float a0 = 0.f, a1 = 0.f, a2 = 0.f, a3 = 0.f;
    const __hip_bfloat16* fms[4] = { f0, f1, f2, f3 };
    const int Wl_[4] = { 176, 88, 44, 22 };
    const int Hl_[4] = { 64, 32, 16, 8 };
    #pragma unroll
    for (int l = 0; l < 4; l++) {
        const int Wl = Wl_[l], Hl = Hl_[l];
        const int HWl = Wl * Hl;
        const float scale = 0.25f / (float)(1 << l);   // W_l/704 == H_l/256
        const __hip_bfloat16* fm = fms[l];
        for (int cp = wave; cp < NCAM * NPT; cp += 4) {
            float X = xyS[cp * 2], Y = xyS[cp * 2 + 1];
            float gx = fmaf(X, scale, -0.5f);
            float gy = fmaf(Y, scale, -0.5f);
            float x0f = floorf(gx), y0f = floorf(gy);
            float fx = gx - x0f, fy = gy - y0f;
            int x0 = (int)x0f, y0 = (int)y0f;
            int x1 = x0 + 1, y1 = y0 + 1;
            bool vx0 = (x0 >= 0) && (x0 < Wl);
            bool vx1 = (x1 >= 0) && (x1 < Wl);
            bool vy0 = (y0 >= 0) && (y0 < Hl);
            bool vy1 = (y1 >= 0) && (y1 < Hl);
            float w00 = (vx0 && vy0) ? (1.f - fx) * (1.f - fy) : 0.f;
            float w01 = (vx1 && vy0) ? fx * (1.f - fy) : 0.f;
            float w10 = (vx0 && vy1) ? (1.f - fx) * fy : 0.f;
            float w11 = (vx1 && vy1) ? fx * fy : 0.f;
            if (w00 + w01 + w10 + w11 == 0.f) continue;   // wave-uniform skip
            int c = cp / NPT, p = cp - c * NPT;
            int xc0 = min(max(x0, 0), Wl - 1), xc1 = min(max(x1, 0), Wl - 1);
            int yc0 = min(max(y0, 0), Hl - 1), yc1 = min(max(y1, 0), Hl - 1);
            const __hip_bfloat16* base = fm + (size_t)c * HWl * EMBED + e0;
            float4 v00 = ld_bf16x4(base + (size_t)(yc0 * Wl + xc0) * EMBED);
            float4 v01 = ld_bf16x4(base + (size_t)(yc0 * Wl + xc1) * EMBED);
            float4 v10 = ld_bf16x4(base + (size_t)(yc1 * Wl + xc0) * EMBED);
            float4 v11 = ld_bf16x4(base + (size_t)(yc1 * Wl + xc1) * EMBED);
            float wg = wS[((c * NLVL + l) * NPT + p) * GPS + g];
            float s0 = w00 * v00.x + w01 * v01.x + w10 * v10.x + w11 * v11.x;
            float s1 = w00 * v00.y + w01 * v01.y + w10 * v10.y + w11 * v11.y;
            float s2 = w00 * v00.z + w01 * v01.z + w10 * v10.z + w11 * v11.z;
            float s3 = w00 * v00.w + w01 * v01.w + w10 * v10.w + w11 * v11.w;
            a0 = fmaf(wg, s0, a0);
            a1 = fmaf(wg, s1, a1);
            a2 = fmaf(wg, s2, a2);
            a3 = fmaf(wg, s3, a3);
        }
    }
    redS[wave][e0 + 0] = a0; redS[wave][e0 + 1] = a1;
    redS[wave][e0 + 2] = a2; redS[wave][e0 + 3] = a3;
    __syncthreads();
    int t = threadIdx.x;
    fused[(size_t)a * EMBED + t] = redS[0][t] + redS[1][t] + redS[2][t] + redS[3][t];
}

// ---------------- K4: out = fused @ w_out + b_out + instance_feature ---------
// block = 4 anchors (one per wave); lanes own 4-col quads (64*4 = 256 cols).
__global__ __launch_bounds__(256) void k_out(const float* __restrict__ fused,
                                             const float* __restrict__ wout,
                                             const float* __restrict__ bout,
                                             const float* __restrict__ inst,
                                             float* __restrict__ out) {
    __shared__ float fS[4][EMBED];
    int wave = threadIdx.x >> 6, lane = threadIdx.x & 63;
    int a = blockIdx.x * 4 + wave;
    *(float4*)&fS[wave][lane * 4] = *(const float4*)&fused[(size_t)a * EMBED + lane * 4];
    // wave-local LDS dependency only: no barrier needed
    int col = lane * 4;
    float4 acc = make_float4(0.f, 0.f, 0.f, 0.f);
    for (int k = 0; k < EMBED; k += 4) {
        float4 f = *(const float4*)&fS[wave][k];
        float4 w0 = *(const float4*)&wout[(size_t)(k + 0) * EMBED + col];
        float4 w1 = *(const float4*)&wout[(size_t)(k + 1) * EMBED + col];
        float4 w2 = *(const float4*)&wout[(size_t)(k + 2) * EMBED + col];
        float4 w3 = *(const float4*)&wout[(size_t)(k + 3) * EMBED + col];
        fma4(acc, f.x, w0); fma4(acc, f.y, w1);
        fma4(acc, f.z, w2); fma4(acc, f.w, w3);
    }
    float4 bv = *(const float4*)&bout[col];
    float4 iv = *(const float4*)&inst[(size_t)a * EMBED + col];
    float4 r;
    r.x = acc.x + bv.x + iv.x; r.y = acc.y + bv.y + iv.y;
    r.z = acc.z + bv.z + iv.z; r.w = acc.w + bv.w + iv.w;
    *(float4*)&out[(size_t)a * EMBED + col] = r;
}

extern "C" void kernel_launch(void* const* d_in, const int* in_sizes, int n_in,
                              void* d_out, int out_size, void* d_ws, size_t ws_size,
                              hipStream_t stream) {
    const float* inst = (const float*)d_in[0];
    const float* anch = (const float*)d_in[1];
    const float* kp   = (const float*)d_in[2];
    const float* fm0  = (const float*)d_in[3];
    const float* fm1  = (const float*)d_in[4];
    const float* fm2  = (const float*)d_in[5];
    const float* fm3  = (const float*)d_in[6];
    const float* proj = (const float*)d_in[7];
    // d_in[8] image_wh: constant (704, 256) folded into level scales
    const float* wlin = (const float*)d_in[9];
    const float* blin = (const float*)d_in[10];
    const float* wout = (const float*)d_in[11];
    const float* bout = (const float*)d_in[12];
    float* out = (float*)d_out;

    char* ws = (char*)d_ws;
    size_t off = 0;
    auto alloc = [&](size_t bytes) -> void* {
        void* p = ws + off;
        off = (off + bytes + 255) & ~(size_t)255;
        return p;
    };
    __hip_bfloat16* t0 = (__hip_bfloat16*)alloc((size_t)NCAM * 11264 * EMBED * 2);
    __hip_bfloat16* t1 = (__hip_bfloat16*)alloc((size_t)NCAM * 2816 * EMBED * 2);
    __hip_bfloat16* t2 = (__hip_bfloat16*)alloc((size_t)NCAM * 704 * EMBED * 2);
    __hip_bfloat16* t3 = (__hip_bfloat16*)alloc((size_t)NCAM * 176 * EMBED * 2);
    float* logits = (float*)alloc((size_t)NANC * NWCOL * 4);      // becomes weights in-place
    float* pxy    = (float*)alloc((size_t)NANC * NCAM * NPT * 2 * 4);
    float* fusedb = (float*)alloc((size_t)NANC * EMBED * 4);

    k_transpose<<<dim3(NCAM * 176), 256, 0, stream>>>(fm0, t0, 11264, 176);
    k_transpose<<<dim3(NCAM * 44),  256, 0, stream>>>(fm1, t1, 2816, 44);
    k_transpose<<<dim3(NCAM * 11),  256, 0, stream>>>(fm2, t2, 704, 11);
    k_transpose<<<dim3(NCAM * 3),   256, 0, stream>>>(fm3, t3, 176, 3);
    k_logits<<<dim3(90, 3), 256, 0, stream>>>(inst, anch, wlin, blin, logits);
    k_softmax<<<dim3(NANC), 256, 0, stream>>>(logits);
    k_project<<<dim3((NANC * NCAM * NPT + 255) / 256), 256, 0, stream>>>(kp, proj, pxy);
    k_aggregate<<<dim3(NANC), 256, 0, stream>>>(t0, t1, t2, t3, logits, pxy, fusedb);
    k_out<<<dim3(NANC / 4), 256, 0, stream>>>(fusedb, wout, bout, inst, out);
}

// Round 2
// 276.077 us; speedup vs baseline: 1.2359x; 1.2359x over previous
//
#include <hip/hip_runtime.h>
#include <hip/hip_bf16.h>
#include <cstdint>

#define EMBED 256
#define GPS 8        // groups
#define NCAM 6
#define NLVL 4
#define NPT 13
#define NANC 900
#define NSAMP (NCAM*NLVL*NPT)   // 312
#define NWCOL (GPS*NSAMP)       // 2496
#define MPAD 928                // 29 tiles of 32 rows

typedef __attribute__((ext_vector_type(8))) short bf16x8;
typedef __attribute__((ext_vector_type(16))) float f32x16;

__device__ __forceinline__ float4 ld_bf16x4(const __hip_bfloat16* p) {
    const ushort4 u = *reinterpret_cast<const ushort4*>(p);
    float4 f;
    f.x = __uint_as_float(((unsigned)u.x) << 16);
    f.y = __uint_as_float(((unsigned)u.y) << 16);
    f.z = __uint_as_float(((unsigned)u.z) << 16);
    f.w = __uint_as_float(((unsigned)u.w) << 16);
    return f;
}

__device__ __forceinline__ ushort bf16bits(float x) {
    __hip_bfloat16 h = __float2bfloat16(x);
    return *reinterpret_cast<ushort*>(&h);
}

// ---------------- K1: fused prep ---------------------------------------------
// block ranges:
//   [0,1056)    fm0 transpose (c,E,HW)->(c,HW,E)bf16   chunks=176
//   [1056,1320) fm1 transpose                          chunks=44
//   [1320,1386) fm2 transpose                          chunks=11
//   [1386,1404) fm3 transpose                          chunks=3
//   [1404,1560) w_weights -> W^T bf16 (LDS 64x64 tile transpose)
//   [1560,1785) featB = bf16(inst+anchor), 225 blocks
//   [1785,1792) featB zero-pad rows 900..927, 7 blocks
//   [1792,2067) projection, 275 blocks
__global__ __launch_bounds__(256) void k_prep(
        const float* __restrict__ fm0, const float* __restrict__ fm1,
        const float* __restrict__ fm2, const float* __restrict__ fm3,
        __hip_bfloat16* __restrict__ t0, __hip_bfloat16* __restrict__ t1,
        __hip_bfloat16* __restrict__ t2, __hip_bfloat16* __restrict__ t3,
        const float* __restrict__ wlin, __hip_bfloat16* __restrict__ wt,
        const float* __restrict__ inst, const float* __restrict__ anch,
        __hip_bfloat16* __restrict__ featB,
        const float* __restrict__ kp, const float* __restrict__ proj,
        float* __restrict__ pxy) {
    __shared__ ushort tile[64][65];
    int b = blockIdx.x;
    int t = threadIdx.x;
    if (b < 1404) {
        // feature-map transpose
        const float* in; __hip_bfloat16* out; int HW, chunks, lb;
        if (b < 1056)      { in = fm0; out = t0; HW = 11264; chunks = 176; lb = b; }
        else if (b < 1320) { in = fm1; out = t1; HW = 2816;  chunks = 44;  lb = b - 1056; }
        else if (b < 1386) { in = fm2; out = t2; HW = 704;   chunks = 11;  lb = b - 1320; }
        else               { in = fm3; out = t3; HW = 176;   chunks = 3;   lb = b - 1386; }
        int c = lb / chunks;
        int hw0 = (lb - c * chunks) * 64;
        const float* src = in + ((size_t)c * EMBED + t) * HW;
        __hip_bfloat16* dst = out + (size_t)c * HW * EMBED + t;
        #pragma unroll
        for (int i = 0; i < 64; i += 4) {
            int hw = hw0 + i;
            if (hw < HW) {
                float4 v = *reinterpret_cast<const float4*>(src + hw);
                dst[(size_t)(hw + 0) * EMBED] = __float2bfloat16(v.x);
                dst[(size_t)(hw + 1) * EMBED] = __float2bfloat16(v.y);
                dst[(size_t)(hw + 2) * EMBED] = __float2bfloat16(v.z);
                dst[(size_t)(hw + 3) * EMBED] = __float2bfloat16(v.w);
            }
        }
    } else if (b < 1560) {
        // W^T: wt[n][k] = bf16(wlin[k][n]); 64x64 tiles, k-tiles=4, n-tiles=39
        int b1 = b - 1404;
        int kt = b1 / 39, nt = b1 - kt * 39;
        int k0 = kt * 64, n0 = nt * 64;
        int grp = t >> 6, nn = t & 63;
        #pragma unroll
        for (int r = 0; r < 16; r++) {
            int kk = grp * 16 + r;
            tile[kk][nn] = bf16bits(wlin[(size_t)(k0 + kk) * NWCOL + n0 + nn]);
        }
        __syncthreads();
        ushort* wtb = reinterpret_cast<ushort*>(wt);
        int kk2 = t & 63;
        #pragma unroll
        for (int r = 0; r < 16; r++) {
            int nn2 = grp * 16 + r;
            wtb[(size_t)(n0 + nn2) * EMBED + k0 + kk2] = tile[kk2][nn2];
        }
    } else if (b < 1785) {
        // featB rows 0..899
        int base = (b - 1560) * 1024 + t * 4;
        float4 a = *(const float4*)&inst[base];
        float4 c = *(const float4*)&anch[base];
        ushort4 r;
        r.x = bf16bits(a.x + c.x); r.y = bf16bits(a.y + c.y);
        r.z = bf16bits(a.z + c.z); r.w = bf16bits(a.w + c.w);
        *reinterpret_cast<ushort4*>(reinterpret_cast<ushort*>(featB) + base) = r;
    } else if (b < 1792) {
        // featB pad rows 900..927 -> zero
        int base = 900 * EMBED + (b - 1785) * 1024 + t * 4;
        ushort4 z; z.x = z.y = z.z = z.w = 0;
        *reinterpret_cast<ushort4*>(reinterpret_cast<ushort*>(featB) + base) = z;
    } else {
        // projection
        int i = (b - 1792) * 256 + t;
        if (i < NANC * NCAM * NPT) {
            int a = i / (NCAM * NPT);
            int r = i - a * (NCAM * NPT);
            int c = r / NPT;
            int p = r - c * NPT;
            const float* M = proj + c * 16;
            const float* k3 = kp + ((size_t)a * NPT + p) * 3;
            float kx = k3[0], ky = k3[1], kz = k3[2];
            float X = M[0] * kx + M[1] * ky + M[2] * kz + M[3];
            float Y = M[4] * kx + M[5] * ky + M[6] * kz + M[7];
            float Z = M[8] * kx + M[9] * ky + M[10] * kz + M[11];
            float invz = 1.f / fmaxf(Z, 1e-5f);
            pxy[(size_t)i * 2 + 0] = X * invz;
            pxy[(size_t)i * 2 + 1] = Y * invz;
        }
    }
}

// ---------------- K2: logits GEMM via MFMA bf16 ------------------------------
// C(900x2496) = featB(928x256,bf16) @ W^T(2496x256,bf16)^T + bias
// wave = one 32x32 tile, mfma_f32_32x32x16_bf16, K-loop 16 steps.
// A frag: lane holds A[m=lane&31][k=(lane>>5)*8+j]; B frag: B[n=lane&31][k=...]
// C/D:    col=lane&31, row=(reg&3)+8*(reg>>2)+4*(lane>>5)   [m74/m101 verified]
#define MT 29
#define NT 78
__global__ __launch_bounds__(256) void k_gemm(const __hip_bfloat16* __restrict__ featB,
                                              const __hip_bfloat16* __restrict__ wt,
                                              const float* __restrict__ blin,
                                              float* __restrict__ logits) {
    int wv = threadIdx.x >> 6, lane = threadIdx.x & 63;
    int idx = blockIdx.x * 4 + wv;
    if (idx >= MT * NT) return;
    int mt = idx % MT, nt = idx / MT;
    int m0 = mt * 32, n0 = nt * 32;
    int l31 = lane & 31;
    int khalf = (lane >> 5) * 8;
    const short* ap = reinterpret_cast<const short*>(featB) + (size_t)(m0 + l31) * EMBED + khalf;
    const short* bp = reinterpret_cast<const short*>(wt)    + (size_t)(n0 + l31) * EMBED + khalf;
    f32x16 acc = {};
    #pragma unroll
    for (int ki = 0; ki < 16; ki++) {
        bf16x8 a = *reinterpret_cast<const bf16x8*>(ap + ki * 16);
        bf16x8 bb = *reinterpret_cast<const bf16x8*>(bp + ki * 16);
        acc = __builtin_amdgcn_mfma_f32_32x32x16_bf16(a, bb, acc, 0, 0, 0);
    }
    float bias = blin[n0 + l31];
    int colg = n0 + l31;
    #pragma unroll
    for (int r = 0; r < 16; r++) {
        int row = (r & 3) + 8 * (r >> 2) + 4 * (lane >> 5);
        int grow = m0 + row;
        if (grow < NANC)
            logits[(size_t)grow * NWCOL + colg] = acc[r] + bias;
    }
}

// ---------------- K3: softmax over 312 samples per (anchor, group), in-place -
__global__ __launch_bounds__(256) void k_softmax(float* __restrict__ w) {
    __shared__ float l[NWCOL];
    __shared__ float gmax[GPS], grs[GPS];
    int a = blockIdx.x;
    for (int j = threadIdx.x; j < NWCOL; j += 256) l[j] = w[(size_t)a * NWCOL + j];
    __syncthreads();
    int g = threadIdx.x >> 5;
    int i = threadIdx.x & 31;
    float m = -1e30f;
    for (int s = i; s < NSAMP; s += 32) m = fmaxf(m, l[s * GPS + g]);
    #pragma unroll
    for (int off = 16; off; off >>= 1) m = fmaxf(m, __shfl_xor(m, off, 32));
    float ssum = 0.f;
    for (int s = i; s < NSAMP; s += 32) ssum += __expf(l[s * GPS + g] - m);
    #pragma unroll
    for (int off = 16; off; off >>= 1) ssum += __shfl_xor(ssum, off, 32);
    if (i == 0) { gmax[g] = m; grs[g] = 1.f / ssum; }
    __syncthreads();
    for (int j = threadIdx.x; j < NWCOL; j += 256) {
        int gg = j & 7;
        w[(size_t)a * NWCOL + j] = __expf(l[j] - gmax[gg]) * grs[gg];
    }
}

// ---------------- K4: bilinear gather + weighted fusion ----------------------
__global__ __launch_bounds__(256) void k_aggregate(const __hip_bfloat16* __restrict__ f0,
                                                   const __hip_bfloat16* __restrict__ f1,
                                                   const __hip_bfloat16* __restrict__ f2,
                                                   const __hip_bfloat16* __restrict__ f3,
                                                   const float* __restrict__ w,
                                                   const float* __restrict__ pxy,
                                                   float* __restrict__ fused) {
    __shared__ float wS[NWCOL];
    __shared__ float xyS[NCAM * NPT * 2];
    __shared__ float redS[4][EMBED];
    int a = blockIdx.x;
    for (int j = threadIdx.x; j < NWCOL; j += 256) wS[j] = w[(size_t)a * NWCOL + j];
    for (int j = threadIdx.x; j < NCAM * NPT * 2; j += 256)
        xyS[j] = pxy[(size_t)a * NCAM * NPT * 2 + j];
    __syncthreads();
    int wave = threadIdx.x >> 6;
    int lane = threadIdx.x & 63;
    int e0 = lane * 4;
    int g = lane >> 3;
    float a0 = 0.f, a1 = 0.f, a2 = 0.f, a3 = 0.f;
    const __hip_bfloat16* fms[4] = { f0, f1, f2, f3 };
    const int Wl_[4] = { 176, 88, 44, 22 };
    const int Hl_[4] = { 64, 32, 16, 8 };
    #pragma unroll
    for (int l = 0; l < 4; l++) {
        const int Wl = Wl_[l], Hl = Hl_[l];
        const int HWl = Wl * Hl;
        const float scale = 0.25f / (float)(1 << l);
        const __hip_bfloat16* fm = fms[l];
        for (int cp = wave; cp < NCAM * NPT; cp += 4) {
            float X = xyS[cp * 2], Y = xyS[cp * 2 + 1];
            float gx = fmaf(X, scale, -0.5f);
            float gy = fmaf(Y, scale, -0.5f);
            float x0f = floorf(gx), y0f = floorf(gy);
            float fx = gx - x0f, fy = gy - y0f;
            int x0 = (int)x0f, y0 = (int)y0f;
            int x1 = x0 + 1, y1 = y0 + 1;
            bool vx0 = (x0 >= 0) && (x0 < Wl);
            bool vx1 = (x1 >= 0) && (x1 < Wl);
            bool vy0 = (y0 >= 0) && (y0 < Hl);
            bool vy1 = (y1 >= 0) && (y1 < Hl);
            float w00 = (vx0 && vy0) ? (1.f - fx) * (1.f - fy) : 0.f;
            float w01 = (vx1 && vy0) ? fx * (1.f - fy) : 0.f;
            float w10 = (vx0 && vy1) ? (1.f - fx) * fy : 0.f;
            float w11 = (vx1 && vy1) ? fx * fy : 0.f;
            if (w00 + w01 + w10 + w11 == 0.f) continue;
            int c = cp / NPT, p = cp - c * NPT;
            int xc0 = min(max(x0, 0), Wl - 1), xc1 = min(max(x1, 0), Wl - 1);
            int yc0 = min(max(y0, 0), Hl - 1), yc1 = min(max(y1, 0), Hl - 1);
            const __hip_bfloat16* base = fm + (size_t)c * HWl * EMBED + e0;
            float4 v00 = ld_bf16x4(base + (size_t)(yc0 * Wl + xc0) * EMBED);
            float4 v01 = ld_bf16x4(base + (size_t)(yc0 * Wl + xc1) * EMBED);
            float4 v10 = ld_bf16x4(base + (size_t)(yc1 * Wl + xc0) * EMBED);
            float4 v11 = ld_bf16x4(base + (size_t)(yc1 * Wl + xc1) * EMBED);
            float wg = wS[((c * NLVL + l) * NPT + p) * GPS + g];
            float s0 = w00 * v00.x + w01 * v01.x + w10 * v10.x + w11 * v11.x;
            float s1 = w00 * v00.y + w01 * v01.y + w10 * v10.y + w11 * v11.y;
            float s2 = w00 * v00.z + w01 * v01.z + w10 * v10.z + w11 * v11.z;
            float s3 = w00 * v00.w + w01 * v01.w + w10 * v10.w + w11 * v11.w;
            a0 = fmaf(wg, s0, a0);
            a1 = fmaf(wg, s1, a1);
            a2 = fmaf(wg, s2, a2);
            a3 = fmaf(wg, s3, a3);
        }
    }
    redS[wave][e0 + 0] = a0; redS[wave][e0 + 1] = a1;
    redS[wave][e0 + 2] = a2; redS[wave][e0 + 3] = a3;
    __syncthreads();
    int t = threadIdx.x;
    fused[(size_t)a * EMBED + t] = redS[0][t] + redS[1][t] + redS[2][t] + redS[3][t];
}

// ---------------- K5: out = fused @ w_out + b_out + instance_feature ---------
__global__ __launch_bounds__(256) void k_out(const float* __restrict__ fused,
                                             const float* __restrict__ wout,
                                             const float* __restrict__ bout,
                                             const float* __restrict__ inst,
                                             float* __restrict__ out) {
    __shared__ float fS[4][EMBED];
    int wave = threadIdx.x >> 6, lane = threadIdx.x & 63;
    int a = blockIdx.x * 4 + wave;
    *(float4*)&fS[wave][lane * 4] = *(const float4*)&fused[(size_t)a * EMBED + lane * 4];
    int col = lane * 4;
    float4 acc = make_float4(0.f, 0.f, 0.f, 0.f);
    for (int k = 0; k < EMBED; k += 4) {
        float4 f = *(const float4*)&fS[wave][k];
        float4 w0 = *(const float4*)&wout[(size_t)(k + 0) * EMBED + col];
        float4 w1 = *(const float4*)&wout[(size_t)(k + 1) * EMBED + col];
        float4 w2 = *(const float4*)&wout[(size_t)(k + 2) * EMBED + col];
        float4 w3 = *(const float4*)&wout[(size_t)(k + 3) * EMBED + col];
        acc.x = fmaf(f.x, w0.x, acc.x); acc.y = fmaf(f.x, w0.y, acc.y);
        acc.z = fmaf(f.x, w0.z, acc.z); acc.w = fmaf(f.x, w0.w, acc.w);
        acc.x = fmaf(f.y, w1.x, acc.x); acc.y = fmaf(f.y, w1.y, acc.y);
        acc.z = fmaf(f.y, w1.z, acc.z); acc.w = fmaf(f.y, w1.w, acc.w);
        acc.x = fmaf(f.z, w2.x, acc.x); acc.y = fmaf(f.z, w2.y, acc.y);
        acc.z = fmaf(f.z, w2.z, acc.z); acc.w = fmaf(f.z, w2.w, acc.w);
        acc.x = fmaf(f.w, w3.x, acc.x); acc.y = fmaf(f.w, w3.y, acc.y);
        acc.z = fmaf(f.w, w3.z, acc.z); acc.w = fmaf(f.w, w3.w, acc.w);
    }
    float4 bv = *(const float4*)&bout[col];
    float4 iv = *(const float4*)&inst[(size_t)a * EMBED + col];
    float4 r;
    r.x = acc.x + bv.x + iv.x; r.y = acc.y + bv.y + iv.y;
    r.z = acc.z + bv.z + iv.z; r.w = acc.w + bv.w + iv.w;
    *(float4*)&out[(size_t)a * EMBED + col] = r;
}

extern "C" void kernel_launch(void* const* d_in, const int* in_sizes, int n_in,
                              void* d_out, int out_size, void* d_ws, size_t ws_size,
                              hipStream_t stream) {
    const float* inst = (const float*)d_in[0];
    const float* anch = (const float*)d_in[1];
    const float* kp   = (const float*)d_in[2];
    const float* fm0  = (const float*)d_in[3];
    const float* fm1  = (const float*)d_in[4];
    const float* fm2  = (const float*)d_in[5];
    const float* fm3  = (const float*)d_in[6];
    const float* proj = (const float*)d_in[7];
    const float* wlin = (const float*)d_in[9];
    const float* blin = (const float*)d_in[10];
    const float* wout = (const float*)d_in[11];
    const float* bout = (const float*)d_in[12];
    float* out = (float*)d_out;

    char* ws = (char*)d_ws;
    size_t off = 0;
    auto alloc = [&](size_t bytes) -> void* {
        void* p = ws + off;
        off = (off + bytes + 255) & ~(size_t)255;
        return p;
    };
    __hip_bfloat16* t0 = (__hip_bfloat16*)alloc((size_t)NCAM * 11264 * EMBED * 2);
    __hip_bfloat16* t1 = (__hip_bfloat16*)alloc((size_t)NCAM * 2816 * EMBED * 2);
    __hip_bfloat16* t2 = (__hip_bfloat16*)alloc((size_t)NCAM * 704 * EMBED * 2);
    __hip_bfloat16* t3 = (__hip_bfloat16*)alloc((size_t)NCAM * 176 * EMBED * 2);
    __hip_bfloat16* wt    = (__hip_bfloat16*)alloc((size_t)NWCOL * EMBED * 2);
    __hip_bfloat16* featB = (__hip_bfloat16*)alloc((size_t)MPAD * EMBED * 2);
    float* logits = (float*)alloc((size_t)NANC * NWCOL * 4);
    float* pxy    = (float*)alloc((size_t)NANC * NCAM * NPT * 2 * 4);
    float* fusedb = (float*)alloc((size_t)NANC * EMBED * 4);

    k_prep<<<dim3(2067), 256, 0, stream>>>(fm0, fm1, fm2, fm3, t0, t1, t2, t3,
                                           wlin, wt, inst, anch, featB, kp, proj, pxy);
    k_gemm<<<dim3((MT * NT + 3) / 4), 256, 0, stream>>>(featB, wt, blin, logits);
    k_softmax<<<dim3(NANC), 256, 0, stream>>>(logits);
    k_aggregate<<<dim3(NANC), 256, 0, stream>>>(t0, t1, t2, t3, logits, pxy, fusedb);
    k_out<<<dim3(NANC / 4), 256, 0, stream>>>(fusedb, wout, bout, inst, out);
}

// Round 3
// 246.508 us; speedup vs baseline: 1.3842x; 1.1199x over previous
//
#include <hip/hip_runtime.h>
#include <hip/hip_bf16.h>
#include <cstdint>

#define EMBED 256
#define GPS 8        // groups
#define NCAM 6
#define NLVL 4
#define NPT 13
#define NANC 900
#define NSAMP (NCAM*NLVL*NPT)   // 312
#define NWCOL (GPS*NSAMP)       // 2496
#define MPAD 928                // 29 tiles of 32 rows

typedef __attribute__((ext_vector_type(8))) short bf16x8;
typedef __attribute__((ext_vector_type(16))) float f32x16;
typedef __attribute__((ext_vector_type(8))) unsigned short ushort8_t;

__device__ __forceinline__ float4 ld_bf16x4(const __hip_bfloat16* p) {
    const ushort4 u = *reinterpret_cast<const ushort4*>(p);
    float4 f;
    f.x = __uint_as_float(((unsigned)u.x) << 16);
    f.y = __uint_as_float(((unsigned)u.y) << 16);
    f.z = __uint_as_float(((unsigned)u.z) << 16);
    f.w = __uint_as_float(((unsigned)u.w) << 16);
    return f;
}

__device__ __forceinline__ ushort bf16bits(float x) {
    __hip_bfloat16 h = __float2bfloat16(x);
    return *reinterpret_cast<ushort*>(&h);
}

// ---------------- K1: fused prep ---------------------------------------------
// block ranges:
//   [0,1056)    fm0 transpose (c,E,HW)->(c,HW,E)bf16   chunks=176
//   [1056,1320) fm1 transpose                          chunks=44
//   [1320,1386) fm2 transpose                          chunks=11
//   [1386,1404) fm3 transpose                          chunks=3 (tail-guarded)
//   [1404,1560) w_weights -> W^T bf16 (LDS 64x64 tile transpose)
//   [1560,1785) featB = bf16(inst+anchor), 225 blocks
//   [1785,1792) featB zero-pad rows 900..927, 7 blocks
//   [1792,2067) projection, 275 blocks
//
// fm transpose: LDS tile 256e x 64hw, layout lds[e][hw^swz(e)], swz(e) =
// ((e>>3)&15)*4 (keeps ushort4 quads contiguous, decorrelates banks for the
// strided phase-2 reads). Phase 1: 16 independent coalesced float4 loads
// (batched for MLP) + ds_write_b64. Phase 2: linear 16-B global stores.
__global__ __launch_bounds__(256) void k_prep(
        const float* __restrict__ fm0, const float* __restrict__ fm1,
        const float* __restrict__ fm2, const float* __restrict__ fm3,
        __hip_bfloat16* __restrict__ t0, __hip_bfloat16* __restrict__ t1,
        __hip_bfloat16* __restrict__ t2, __hip_bfloat16* __restrict__ t3,
        const float* __restrict__ wlin, __hip_bfloat16* __restrict__ wt,
        const float* __restrict__ inst, const float* __restrict__ anch,
        __hip_bfloat16* __restrict__ featB,
        const float* __restrict__ kp, const float* __restrict__ proj,
        float* __restrict__ pxy) {
    __shared__ ushort lds2[256 * 64];     // 32 KiB, shared by both transposes
    int b = blockIdx.x;
    int t = threadIdx.x;
    if (b < 1404) {
        const float* in; __hip_bfloat16* outp; int HW, chunks, lb;
        if (b < 1056)      { in = fm0; outp = t0; HW = 11264; chunks = 176; lb = b; }
        else if (b < 1320) { in = fm1; outp = t1; HW = 2816;  chunks = 44;  lb = b - 1056; }
        else if (b < 1386) { in = fm2; outp = t2; HW = 704;   chunks = 11;  lb = b - 1320; }
        else               { in = fm3; outp = t3; HW = 176;   chunks = 3;   lb = b - 1386; }
        int c = lb / chunks;
        int hw0 = (lb - c * chunks) * 64;
        int q = t & 15, eg = t >> 4;
        bool vld = (hw0 + q * 4 + 3) < HW;          // quad fully in-range
        const float* srcq = in + (size_t)c * EMBED * HW + hw0 + q * 4;
        // phase 1: 16 independent loads first (MLP), then convert + LDS write
        float4 vals[16];
        #pragma unroll
        for (int r = 0; r < 16; r++) {
            int e = eg + r * 16;
            vals[r] = vld ? *(const float4*)(srcq + (size_t)e * HW)
                          : make_float4(0.f, 0.f, 0.f, 0.f);
        }
        #pragma unroll
        for (int r = 0; r < 16; r++) {
            int e = eg + r * 16;
            int sw = ((e >> 3) & 15) * 4;
            ushort4 u;
            u.x = bf16bits(vals[r].x); u.y = bf16bits(vals[r].y);
            u.z = bf16bits(vals[r].z); u.w = bf16bits(vals[r].w);
            *reinterpret_cast<ushort4*>(&lds2[e * 64 + ((q * 4) ^ sw)]) = u;
        }
        __syncthreads();
        // phase 2: linear ushort8 stores over the (64hw x 256e) output chunk
        ushort* outb = reinterpret_cast<ushort*>(outp) + ((size_t)c * HW + hw0) * EMBED;
        #pragma unroll
        for (int r = 0; r < 8; r++) {
            int flat = r * 2048 + t * 8;
            int hw = flat >> 8;
            int e0 = flat & 255;
            if (hw0 + hw < HW) {
                ushort8_t u;
                #pragma unroll
                for (int j = 0; j < 8; j++) {
                    int e = e0 + j;
                    int sw = ((e >> 3) & 15) * 4;
                    u[j] = lds2[e * 64 + (hw ^ sw)];
                }
                *reinterpret_cast<ushort8_t*>(outb + flat) = u;
            }
        }
    } else if (b < 1560) {
        // W^T: wt[n][k] = bf16(wlin[k][n]); 64x64 tiles (tile stride 65)
        int b1 = b - 1404;
        int kt = b1 / 39, nt = b1 - kt * 39;
        int k0 = kt * 64, n0 = nt * 64;
        int grp = t >> 6, nn = t & 63;
        #pragma unroll
        for (int r = 0; r < 16; r++) {
            int kk = grp * 16 + r;
            lds2[kk * 65 + nn] = bf16bits(wlin[(size_t)(k0 + kk) * NWCOL + n0 + nn]);
        }
        __syncthreads();
        ushort* wtb = reinterpret_cast<ushort*>(wt);
        int kk2 = t & 63;
        #pragma unroll
        for (int r = 0; r < 16; r++) {
            int nn2 = grp * 16 + r;
            wtb[(size_t)(n0 + nn2) * EMBED + k0 + kk2] = lds2[kk2 * 65 + nn2];
        }
    } else if (b < 1785) {
        int base = (b - 1560) * 1024 + t * 4;
        float4 a = *(const float4*)&inst[base];
        float4 c = *(const float4*)&anch[base];
        ushort4 r;
        r.x = bf16bits(a.x + c.x); r.y = bf16bits(a.y + c.y);
        r.z = bf16bits(a.z + c.z); r.w = bf16bits(a.w + c.w);
        *reinterpret_cast<ushort4*>(reinterpret_cast<ushort*>(featB) + base) = r;
    } else if (b < 1792) {
        int base = 900 * EMBED + (b - 1785) * 1024 + t * 4;
        ushort4 z; z.x = z.y = z.z = z.w = 0;
        *reinterpret_cast<ushort4*>(reinterpret_cast<ushort*>(featB) + base) = z;
    } else {
        int i = (b - 1792) * 256 + t;
        if (i < NANC * NCAM * NPT) {
            int a = i / (NCAM * NPT);
            int r = i - a * (NCAM * NPT);
            int c = r / NPT;
            int p = r - c * NPT;
            const float* M = proj + c * 16;
            const float* k3 = kp + ((size_t)a * NPT + p) * 3;
            float kx = k3[0], ky = k3[1], kz = k3[2];
            float X = M[0] * kx + M[1] * ky + M[2] * kz + M[3];
            float Y = M[4] * kx + M[5] * ky + M[6] * kz + M[7];
            float Z = M[8] * kx + M[9] * ky + M[10] * kz + M[11];
            float invz = 1.f / fmaxf(Z, 1e-5f);
            pxy[(size_t)i * 2 + 0] = X * invz;
            pxy[(size_t)i * 2 + 1] = Y * invz;
        }
    }
}

// ---------------- K2: logits GEMM via MFMA bf16 ------------------------------
#define MT 29
#define NT 78
__global__ __launch_bounds__(256) void k_gemm(const __hip_bfloat16* __restrict__ featB,
                                              const __hip_bfloat16* __restrict__ wt,
                                              const float* __restrict__ blin,
                                              float* __restrict__ logits) {
    int wv = threadIdx.x >> 6, lane = threadIdx.x & 63;
    int idx = blockIdx.x * 4 + wv;
    if (idx >= MT * NT) return;
    int mt = idx % MT, nt = idx / MT;
    int m0 = mt * 32, n0 = nt * 32;
    int l31 = lane & 31;
    int khalf = (lane >> 5) * 8;
    const short* ap = reinterpret_cast<const short*>(featB) + (size_t)(m0 + l31) * EMBED + khalf;
    const short* bp = reinterpret_cast<const short*>(wt)    + (size_t)(n0 + l31) * EMBED + khalf;
    f32x16 acc = {};
    #pragma unroll
    for (int ki = 0; ki < 16; ki++) {
        bf16x8 a = *reinterpret_cast<const bf16x8*>(ap + ki * 16);
        bf16x8 bb = *reinterpret_cast<const bf16x8*>(bp + ki * 16);
        acc = __builtin_amdgcn_mfma_f32_32x32x16_bf16(a, bb, acc, 0, 0, 0);
    }
    float bias = blin[n0 + l31];
    int colg = n0 + l31;
    #pragma unroll
    for (int r = 0; r < 16; r++) {
        int row = (r & 3) + 8 * (r >> 2) + 4 * (lane >> 5);
        int grow = m0 + row;
        if (grow < NANC)
            logits[(size_t)grow * NWCOL + colg] = acc[r] + bias;
    }
}

// ---------------- K3: softmax (fused) + bilinear gather + fusion -------------
__global__ __launch_bounds__(256) void k_aggregate(const __hip_bfloat16* __restrict__ f0,
                                                   const __hip_bfloat16* __restrict__ f1,
                                                   const __hip_bfloat16* __restrict__ f2,
                                                   const __hip_bfloat16* __restrict__ f3,
                                                   const float* __restrict__ logits,
                                                   const float* __restrict__ pxy,
                                                   float* __restrict__ fused) {
    __shared__ float wS[NWCOL];
    __shared__ float xyS[NCAM * NPT * 2];
    __shared__ float redS[4][EMBED];
    __shared__ float gmax[GPS], grs[GPS];
    int a = blockIdx.x;
    for (int j = threadIdx.x; j < NWCOL; j += 256) wS[j] = logits[(size_t)a * NWCOL + j];
    for (int j = threadIdx.x; j < NCAM * NPT * 2; j += 256)
        xyS[j] = pxy[(size_t)a * NCAM * NPT * 2 + j];
    __syncthreads();
    // fused per-(anchor,group) softmax over 312 samples: 8 teams of 32 lanes
    {
        int g = threadIdx.x >> 5;
        int i = threadIdx.x & 31;
        float m = -1e30f;
        for (int s = i; s < NSAMP; s += 32) m = fmaxf(m, wS[s * GPS + g]);
        #pragma unroll
        for (int off = 16; off; off >>= 1) m = fmaxf(m, __shfl_xor(m, off, 32));
        float ssum = 0.f;
        for (int s = i; s < NSAMP; s += 32) ssum += __expf(wS[s * GPS + g] - m);
        #pragma unroll
        for (int off = 16; off; off >>= 1) ssum += __shfl_xor(ssum, off, 32);
        if (i == 0) { gmax[g] = m; grs[g] = 1.f / ssum; }
    }
    __syncthreads();
    for (int j = threadIdx.x; j < NWCOL; j += 256) {
        int gg = j & 7;
        wS[j] = __expf(wS[j] - gmax[gg]) * grs[gg];
    }
    __syncthreads();
    int wave = threadIdx.x >> 6;
    int lane = threadIdx.x & 63;
    int e0 = lane * 4;
    int g = lane >> 3;
    float a0 = 0.f, a1 = 0.f, a2 = 0.f, a3 = 0.f;
    const __hip_bfloat16* fms[4] = { f0, f1, f2, f3 };
    const int Wl_[4] = { 176, 88, 44, 22 };
    const int Hl_[4] = { 64, 32, 16, 8 };
    #pragma unroll
    for (int l = 0; l < 4; l++) {
        const int Wl = Wl_[l], Hl = Hl_[l];
        const int HWl = Wl * Hl;
        const float scale = 0.25f / (float)(1 << l);
        const __hip_bfloat16* fm = fms[l];
        for (int cp = wave; cp < NCAM * NPT; cp += 4) {
            float X = xyS[cp * 2], Y = xyS[cp * 2 + 1];
            float gx = fmaf(X, scale, -0.5f);
            float gy = fmaf(Y, scale, -0.5f);
            float x0f = floorf(gx), y0f = floorf(gy);
            float fx = gx - x0f, fy = gy - y0f;
            int x0 = (int)x0f, y0 = (int)y0f;
            int x1 = x0 + 1, y1 = y0 + 1;
            bool vx0 = (x0 >= 0) && (x0 < Wl);
            bool vx1 = (x1 >= 0) && (x1 < Wl);
            bool vy0 = (y0 >= 0) && (y0 < Hl);
            bool vy1 = (y1 >= 0) && (y1 < Hl);
            float w00 = (vx0 && vy0) ? (1.f - fx) * (1.f - fy) : 0.f;
            float w01 = (vx1 && vy0) ? fx * (1.f - fy) : 0.f;
            float w10 = (vx0 && vy1) ? (1.f - fx) * fy : 0.f;
            float w11 = (vx1 && vy1) ? fx * fy : 0.f;
            if (w00 + w01 + w10 + w11 == 0.f) continue;
            int c = cp / NPT, p = cp - c * NPT;
            int xc0 = min(max(x0, 0), Wl - 1), xc1 = min(max(x1, 0), Wl - 1);
            int yc0 = min(max(y0, 0), Hl - 1), yc1 = min(max(y1, 0), Hl - 1);
            const __hip_bfloat16* base = fm + (size_t)c * HWl * EMBED + e0;
            float4 v00 = ld_bf16x4(base + (size_t)(yc0 * Wl + xc0) * EMBED);
            float4 v01 = ld_bf16x4(base + (size_t)(yc0 * Wl + xc1) * EMBED);
            float4 v10 = ld_bf16x4(base + (size_t)(yc1 * Wl + xc0) * EMBED);
            float4 v11 = ld_bf16x4(base + (size_t)(yc1 * Wl + xc1) * EMBED);
            float wg = wS[((c * NLVL + l) * NPT + p) * GPS + g];
            float s0 = w00 * v00.x + w01 * v01.x + w10 * v10.x + w11 * v11.x;
            float s1 = w00 * v00.y + w01 * v01.y + w10 * v10.y + w11 * v11.y;
            float s2 = w00 * v00.z + w01 * v01.z + w10 * v10.z + w11 * v11.z;
            float s3 = w00 * v00.w + w01 * v01.w + w10 * v10.w + w11 * v11.w;
            a0 = fmaf(wg, s0, a0);
            a1 = fmaf(wg, s1, a1);
            a2 = fmaf(wg, s2, a2);
            a3 = fmaf(wg, s3, a3);
        }
    }
    redS[wave][e0 + 0] = a0; redS[wave][e0 + 1] = a1;
    redS[wave][e0 + 2] = a2; redS[wave][e0 + 3] = a3;
    __syncthreads();
    int t = threadIdx.x;
    fused[(size_t)a * EMBED + t] = redS[0][t] + redS[1][t] + redS[2][t] + redS[3][t];
}

// ---------------- K4: out = fused @ w_out + b_out + instance_feature ---------
__global__ __launch_bounds__(256) void k_out(const float* __restrict__ fused,
                                             const float* __restrict__ wout,
                                             const float* __restrict__ bout,
                                             const float* __restrict__ inst,
                                             float* __restrict__ out) {
    __shared__ float fS[4][EMBED];
    int wave = threadIdx.x >> 6, lane = threadIdx.x & 63;
    int a = blockIdx.x * 4 + wave;
    *(float4*)&fS[wave][lane * 4] = *(const float4*)&fused[(size_t)a * EMBED + lane * 4];
    int col = lane * 4;
    float4 acc = make_float4(0.f, 0.f, 0.f, 0.f);
    for (int k = 0; k < EMBED; k += 4) {
        float4 f = *(const float4*)&fS[wave][k];
        float4 w0 = *(const float4*)&wout[(size_t)(k + 0) * EMBED + col];
        float4 w1 = *(const float4*)&wout[(size_t)(k + 1) * EMBED + col];
        float4 w2 = *(const float4*)&wout[(size_t)(k + 2) * EMBED + col];
        float4 w3 = *(const float4*)&wout[(size_t)(k + 3) * EMBED + col];
        acc.x = fmaf(f.x, w0.x, acc.x); acc.y = fmaf(f.x, w0.y, acc.y);
        acc.z = fmaf(f.x, w0.z, acc.z); acc.w = fmaf(f.x, w0.w, acc.w);
        acc.x = fmaf(f.y, w1.x, acc.x); acc.y = fmaf(f.y, w1.y, acc.y);
        acc.z = fmaf(f.y, w1.z, acc.z); acc.w = fmaf(f.y, w1.w, acc.w);
        acc.x = fmaf(f.z, w2.x, acc.x); acc.y = fmaf(f.z, w2.y, acc.y);
        acc.z = fmaf(f.z, w2.z, acc.z); acc.w = fmaf(f.z, w2.w, acc.w);
        acc.x = fmaf(f.w, w3.x, acc.x); acc.y = fmaf(f.w, w3.y, acc.y);
        acc.z = fmaf(f.w, w3.z, acc.z); acc.w = fmaf(f.w, w3.w, acc.w);
    }
    float4 bv = *(const float4*)&bout[col];
    float4 iv = *(const float4*)&inst[(size_t)a * EMBED + col];
    float4 r;
    r.x = acc.x + bv.x + iv.x; r.y = acc.y + bv.y + iv.y;
    r.z = acc.z + bv.z + iv.z; r.w = acc.w + bv.w + iv.w;
    *(float4*)&out[(size_t)a * EMBED + col] = r;
}

extern "C" void kernel_launch(void* const* d_in, const int* in_sizes, int n_in,
                              void* d_out, int out_size, void* d_ws, size_t ws_size,
                              hipStream_t stream) {
    const float* inst = (const float*)d_in[0];
    const float* anch = (const float*)d_in[1];
    const float* kp   = (const float*)d_in[2];
    const float* fm0  = (const float*)d_in[3];
    const float* fm1  = (const float*)d_in[4];
    const float* fm2  = (const float*)d_in[5];
    const float* fm3  = (const float*)d_in[6];
    const float* proj = (const float*)d_in[7];
    const float* wlin = (const float*)d_in[9];
    const float* blin = (const float*)d_in[10];
    const float* wout = (const float*)d_in[11];
    const float* bout = (const float*)d_in[12];
    float* out = (float*)d_out;

    char* ws = (char*)d_ws;
    size_t off = 0;
    auto alloc = [&](size_t bytes) -> void* {
        void* p = ws + off;
        off = (off + bytes + 255) & ~(size_t)255;
        return p;
    };
    __hip_bfloat16* t0 = (__hip_bfloat16*)alloc((size_t)NCAM * 11264 * EMBED * 2);
    __hip_bfloat16* t1 = (__hip_bfloat16*)alloc((size_t)NCAM * 2816 * EMBED * 2);
    __hip_bfloat16* t2 = (__hip_bfloat16*)alloc((size_t)NCAM * 704 * EMBED * 2);
    __hip_bfloat16* t3 = (__hip_bfloat16*)alloc((size_t)NCAM * 176 * EMBED * 2);
    __hip_bfloat16* wt    = (__hip_bfloat16*)alloc((size_t)NWCOL * EMBED * 2);
    __hip_bfloat16* featB = (__hip_bfloat16*)alloc((size_t)MPAD * EMBED * 2);
    float* logits = (float*)alloc((size_t)NANC * NWCOL * 4);
    float* pxy    = (float*)alloc((size_t)NANC * NCAM * NPT * 2 * 4);
    float* fusedb = (float*)alloc((size_t)NANC * EMBED * 4);

    k_prep<<<dim3(2067), 256, 0, stream>>>(fm0, fm1, fm2, fm3, t0, t1, t2, t3,
                                           wlin, wt, inst, anch, featB, kp, proj, pxy);
    k_gemm<<<dim3((MT * NT + 3) / 4), 256, 0, stream>>>(featB, wt, blin, logits);
    k_aggregate<<<dim3(NANC), 256, 0, stream>>>(t0, t1, t2, t3, logits, pxy, fusedb);
    k_out<<<dim3(NANC / 4), 256, 0, stream>>>(fusedb, wout, bout, inst, out);
}

// Round 4
// 221.545 us; speedup vs baseline: 1.5402x; 1.1127x over previous
//
#include <hip/hip_runtime.h>
#include <hip/hip_bf16.h>
#include <hip/hip_fp16.h>
#include <cstdint>

#define EMBED 256
#define GPS 8        // groups
#define NCAM 6
#define NLVL 4
#define NPT 13
#define NANC 900
#define NSAMP (NCAM*NLVL*NPT)   // 312
#define NWCOL (GPS*NSAMP)       // 2496
#define MPAD 928                // 29 tiles of 32 rows
#define WSTRIDE 328             // LDS stride for [g][s] weights (conflict-free)

typedef __attribute__((ext_vector_type(8))) short bf16x8;
typedef __attribute__((ext_vector_type(16))) float f32x16;
typedef __attribute__((ext_vector_type(8))) unsigned short ushort8_t;

__device__ __forceinline__ ushort bf16bits(float x) {
    __hip_bfloat16 h = __float2bfloat16(x);
    return *reinterpret_cast<ushort*>(&h);
}
__device__ __forceinline__ ushort h16bits(float x) {
    __half h = __float2half(x);
    return *reinterpret_cast<ushort*>(&h);
}
__device__ __forceinline__ __half2 u2h2(unsigned u) {
    union { unsigned u; __half2 h; } cv; cv.u = u; return cv.h;
}

// ---------------- K1: fused prep ---------------------------------------------
// block ranges:
//   [0,1056)    fm0 transpose (c,E,HW)->(c,HW,E) f16   chunks=176
//   [1056,1320) fm1 transpose                          chunks=44
//   [1320,1386) fm2 transpose                          chunks=11
//   [1386,1404) fm3 transpose                          chunks=3 (tail-guarded)
//   [1404,1560) w_weights -> W^T bf16 (LDS 64x64 tile transpose)
//   [1560,1785) featB = bf16(inst+anchor), 225 blocks
//   [1785,1792) featB zero-pad rows 900..927, 7 blocks
//   [1792,2067) projection, 275 blocks
__global__ __launch_bounds__(256) void k_prep(
        const float* __restrict__ fm0, const float* __restrict__ fm1,
        const float* __restrict__ fm2, const float* __restrict__ fm3,
        __half* __restrict__ t0, __half* __restrict__ t1,
        __half* __restrict__ t2, __half* __restrict__ t3,
        const float* __restrict__ wlin, __hip_bfloat16* __restrict__ wt,
        const float* __restrict__ inst, const float* __restrict__ anch,
        __hip_bfloat16* __restrict__ featB,
        const float* __restrict__ kp, const float* __restrict__ proj,
        float* __restrict__ pxy) {
    __shared__ ushort lds2[256 * 64];     // 32 KiB, shared by both transposes
    int b = blockIdx.x;
    int t = threadIdx.x;
    if (b < 1404) {
        const float* in; __half* outp; int HW, chunks, lb;
        if (b < 1056)      { in = fm0; outp = t0; HW = 11264; chunks = 176; lb = b; }
        else if (b < 1320) { in = fm1; outp = t1; HW = 2816;  chunks = 44;  lb = b - 1056; }
        else if (b < 1386) { in = fm2; outp = t2; HW = 704;   chunks = 11;  lb = b - 1320; }
        else               { in = fm3; outp = t3; HW = 176;   chunks = 3;   lb = b - 1386; }
        int c = lb / chunks;
        int hw0 = (lb - c * chunks) * 64;
        int q = t & 15, eg = t >> 4;
        bool vld = (hw0 + q * 4 + 3) < HW;
        const float* srcq = in + (size_t)c * EMBED * HW + hw0 + q * 4;
        float4 vals[16];
        #pragma unroll
        for (int r = 0; r < 16; r++) {
            int e = eg + r * 16;
            vals[r] = vld ? *(const float4*)(srcq + (size_t)e * HW)
                          : make_float4(0.f, 0.f, 0.f, 0.f);
        }
        #pragma unroll
        for (int r = 0; r < 16; r++) {
            int e = eg + r * 16;
            int sw = ((e >> 3) & 15) * 4;
            ushort4 u;
            u.x = h16bits(vals[r].x); u.y = h16bits(vals[r].y);
            u.z = h16bits(vals[r].z); u.w = h16bits(vals[r].w);
            *reinterpret_cast<ushort4*>(&lds2[e * 64 + ((q * 4) ^ sw)]) = u;
        }
        __syncthreads();
        ushort* outb = reinterpret_cast<ushort*>(outp) + ((size_t)c * HW + hw0) * EMBED;
        #pragma unroll
        for (int r = 0; r < 8; r++) {
            int flat = r * 2048 + t * 8;
            int hw = flat >> 8;
            int e0 = flat & 255;
            if (hw0 + hw < HW) {
                ushort8_t u;
                #pragma unroll
                for (int j = 0; j < 8; j++) {
                    int e = e0 + j;
                    int sw = ((e >> 3) & 15) * 4;
                    u[j] = lds2[e * 64 + (hw ^ sw)];
                }
                *reinterpret_cast<ushort8_t*>(outb + flat) = u;
            }
        }
    } else if (b < 1560) {
        // W^T: wt[n][k] = bf16(wlin[k][n]); 64x64 tiles (tile stride 65)
        int b1 = b - 1404;
        int kt = b1 / 39, nt = b1 - kt * 39;
        int k0 = kt * 64, n0 = nt * 64;
        int grp = t >> 6, nn = t & 63;
        #pragma unroll
        for (int r = 0; r < 16; r++) {
            int kk = grp * 16 + r;
            lds2[kk * 65 + nn] = bf16bits(wlin[(size_t)(k0 + kk) * NWCOL + n0 + nn]);
        }
        __syncthreads();
        ushort* wtb = reinterpret_cast<ushort*>(wt);
        int kk2 = t & 63;
        #pragma unroll
        for (int r = 0; r < 16; r++) {
            int nn2 = grp * 16 + r;
            wtb[(size_t)(n0 + nn2) * EMBED + k0 + kk2] = lds2[kk2 * 65 + nn2];
        }
    } else if (b < 1785) {
        int base = (b - 1560) * 1024 + t * 4;
        float4 a = *(const float4*)&inst[base];
        float4 c = *(const float4*)&anch[base];
        ushort4 r;
        r.x = bf16bits(a.x + c.x); r.y = bf16bits(a.y + c.y);
        r.z = bf16bits(a.z + c.z); r.w = bf16bits(a.w + c.w);
        *reinterpret_cast<ushort4*>(reinterpret_cast<ushort*>(featB) + base) = r;
    } else if (b < 1792) {
        int base = 900 * EMBED + (b - 1785) * 1024 + t * 4;
        ushort4 z; z.x = z.y = z.z = z.w = 0;
        *reinterpret_cast<ushort4*>(reinterpret_cast<ushort*>(featB) + base) = z;
    } else {
        int i = (b - 1792) * 256 + t;
        if (i < NANC * NCAM * NPT) {
            int a = i / (NCAM * NPT);
            int r = i - a * (NCAM * NPT);
            int c = r / NPT;
            int p = r - c * NPT;
            const float* M = proj + c * 16;
            const float* k3 = kp + ((size_t)a * NPT + p) * 3;
            float kx = k3[0], ky = k3[1], kz = k3[2];
            float X = M[0] * kx + M[1] * ky + M[2] * kz + M[3];
            float Y = M[4] * kx + M[5] * ky + M[6] * kz + M[7];
            float Z = M[8] * kx + M[9] * ky + M[10] * kz + M[11];
            float invz = 1.f / fmaxf(Z, 1e-5f);
            pxy[(size_t)i * 2 + 0] = X * invz;
            pxy[(size_t)i * 2 + 1] = Y * invz;
        }
    }
}

// ---------------- K2: logits GEMM via MFMA bf16 ------------------------------
#define MT 29
#define NT 78
__global__ __launch_bounds__(256) void k_gemm(const __hip_bfloat16* __restrict__ featB,
                                              const __hip_bfloat16* __restrict__ wt,
                                              const float* __restrict__ blin,
                                              float* __restrict__ logits) {
    int wv = threadIdx.x >> 6, lane = threadIdx.x & 63;
    int idx = blockIdx.x * 4 + wv;
    if (idx >= MT * NT) return;
    int mt = idx % MT, nt = idx / MT;
    int m0 = mt * 32, n0 = nt * 32;
    int l31 = lane & 31;
    int khalf = (lane >> 5) * 8;
    const short* ap = reinterpret_cast<const short*>(featB) + (size_t)(m0 + l31) * EMBED + khalf;
    const short* bp = reinterpret_cast<const short*>(wt)    + (size_t)(n0 + l31) * EMBED + khalf;
    f32x16 acc = {};
    #pragma unroll 8
    for (int ki = 0; ki < 16; ki++) {
        bf16x8 a = *reinterpret_cast<const bf16x8*>(ap + ki * 16);
        bf16x8 bb = *reinterpret_cast<const bf16x8*>(bp + ki * 16);
        acc = __builtin_amdgcn_mfma_f32_32x32x16_bf16(a, bb, acc, 0, 0, 0);
    }
    float bias = blin[n0 + l31];
    int colg = n0 + l31;
    #pragma unroll
    for (int r = 0; r < 16; r++) {
        int row = (r & 3) + 8 * (r >> 2) + 4 * (lane >> 5);
        int grow = m0 + row;
        if (grow < NANC)
            logits[(size_t)grow * NWCOL + colg] = acc[r] + bias;
    }
}

// ---------------- K3: softmax + bilinear gather + fusion + out-proj ----------
// 512 threads = 8 waves. Weights staged transposed [g][s] (stride 328:
// conflict-free softmax scans + 8-distinct-bank broadcast in gather loop).
// Waves split the 78 (cam,pt) pairs 8-ways; f16 packed blend; epilogue does
// fused @ w_out + b_out + inst directly to d_out.
__global__ __launch_bounds__(512) void k_aggregate(const __half* __restrict__ f0,
                                                   const __half* __restrict__ f1,
                                                   const __half* __restrict__ f2,
                                                   const __half* __restrict__ f3,
                                                   const float* __restrict__ logits,
                                                   const float* __restrict__ pxy,
                                                   const float* __restrict__ wout,
                                                   const float* __restrict__ bout,
                                                   const float* __restrict__ inst,
                                                   float* __restrict__ out) {
    __shared__ float wT[GPS * WSTRIDE];    // 10496 B
    __shared__ float xyS[NCAM * NPT * 2];  // 624 B
    __shared__ float redS[8][EMBED];       // 8192 B
    __shared__ float pS[EMBED];            // 1024 B
    int a = blockIdx.x;
    int tid = threadIdx.x;
    for (int j = tid; j < NWCOL; j += 512)
        wT[(j & 7) * WSTRIDE + (j >> 3)] = logits[(size_t)a * NWCOL + j];
    for (int j = tid; j < NCAM * NPT * 2; j += 512)
        xyS[j] = pxy[(size_t)a * NCAM * NPT * 2 + j];
    __syncthreads();
    int wave = tid >> 6;
    int lane = tid & 63;
    // softmax: wave g owns group g, 64 lanes scan s
    {
        int g = wave;
        float m = -1e30f;
        for (int s = lane; s < NSAMP; s += 64) m = fmaxf(m, wT[g * WSTRIDE + s]);
        #pragma unroll
        for (int off = 32; off; off >>= 1) m = fmaxf(m, __shfl_xor(m, off));
        float ssum = 0.f;
        for (int s = lane; s < NSAMP; s += 64) ssum += __expf(wT[g * WSTRIDE + s] - m);
        #pragma unroll
        for (int off = 32; off; off >>= 1) ssum += __shfl_xor(ssum, off);
        float rs = 1.f / ssum;
        for (int s = lane; s < NSAMP; s += 64)
            wT[g * WSTRIDE + s] = __expf(wT[g * WSTRIDE + s] - m) * rs;
    }
    __syncthreads();
    int e0 = lane * 4;
    int g = lane >> 3;
    float a0 = 0.f, a1 = 0.f, a2 = 0.f, a3 = 0.f;
    const __half* fms[4] = { f0, f1, f2, f3 };
    const int Wl_[4] = { 176, 88, 44, 22 };
    const int Hl_[4] = { 64, 32, 16, 8 };
    #pragma unroll
    for (int l = 0; l < 4; l++) {
        const int Wl = Wl_[l], Hl = Hl_[l];
        const int HWl = Wl * Hl;
        const float scale = 0.25f / (float)(1 << l);
        const __half* fm = fms[l];
        for (int cp = wave; cp < NCAM * NPT; cp += 8) {
            float X = xyS[cp * 2], Y = xyS[cp * 2 + 1];
            float gx = fmaf(X, scale, -0.5f);
            float gy = fmaf(Y, scale, -0.5f);
            float x0f = floorf(gx), y0f = floorf(gy);
            float fx = gx - x0f, fy = gy - y0f;
            int x0 = (int)x0f, y0 = (int)y0f;
            int x1 = x0 + 1, y1 = y0 + 1;
            bool vx0 = (x0 >= 0) && (x0 < Wl);
            bool vx1 = (x1 >= 0) && (x1 < Wl);
            bool vy0 = (y0 >= 0) && (y0 < Hl);
            bool vy1 = (y1 >= 0) && (y1 < Hl);
            float w00 = (vx0 && vy0) ? (1.f - fx) * (1.f - fy) : 0.f;
            float w01 = (vx1 && vy0) ? fx * (1.f - fy) : 0.f;
            float w10 = (vx0 && vy1) ? (1.f - fx) * fy : 0.f;
            float w11 = (vx1 && vy1) ? fx * fy : 0.f;
            if (w00 + w01 + w10 + w11 == 0.f) continue;   // wave-uniform skip
            int c = cp / NPT, p = cp - c * NPT;
            int xc0 = min(max(x0, 0), Wl - 1), xc1 = min(max(x1, 0), Wl - 1);
            int yc0 = min(max(y0, 0), Hl - 1), yc1 = min(max(y1, 0), Hl - 1);
            const __half* base = fm + (size_t)c * HWl * EMBED + e0;
            uint2 u00 = *(const uint2*)(base + (size_t)(yc0 * Wl + xc0) * EMBED);
            uint2 u01 = *(const uint2*)(base + (size_t)(yc0 * Wl + xc1) * EMBED);
            uint2 u10 = *(const uint2*)(base + (size_t)(yc1 * Wl + xc0) * EMBED);
            uint2 u11 = *(const uint2*)(base + (size_t)(yc1 * Wl + xc1) * EMBED);
            __half2 W00 = __float2half2_rn(w00), W01 = __float2half2_rn(w01);
            __half2 W10 = __float2half2_rn(w10), W11 = __float2half2_rn(w11);
            __half2 blo = __hfma2(u2h2(u00.x), W00,
                          __hfma2(u2h2(u01.x), W01,
                          __hfma2(u2h2(u10.x), W10,
                          __hmul2(u2h2(u11.x), W11))));
            __half2 bhi = __hfma2(u2h2(u00.y), W00,
                          __hfma2(u2h2(u01.y), W01,
                          __hfma2(u2h2(u10.y), W10,
                          __hmul2(u2h2(u11.y), W11))));
            float2 flo = __half22float2(blo);
            float2 fhi = __half22float2(bhi);
            float wg = wT[g * WSTRIDE + (c * NLVL + l) * NPT + p];
            a0 = fmaf(wg, flo.x, a0);
            a1 = fmaf(wg, flo.y, a1);
            a2 = fmaf(wg, fhi.x, a2);
            a3 = fmaf(wg, fhi.y, a3);
        }
    }
    redS[wave][e0 + 0] = a0; redS[wave][e0 + 1] = a1;
    redS[wave][e0 + 2] = a2; redS[wave][e0 + 3] = a3;
    __syncthreads();
    // epilogue: fused @ w_out + b_out + inst  (K split across two half-blocks)
    int col = tid & 255;
    int kh = tid >> 8;
    if (kh == 0) {
        float s = redS[0][col] + redS[1][col] + redS[2][col] + redS[3][col]
                + redS[4][col] + redS[5][col] + redS[6][col] + redS[7][col];
        redS[0][col] = s;    // in-place: each col touched by exactly one thread
    }
    __syncthreads();
    float acc = 0.f;
    int kbase = kh * 128;
    #pragma unroll 8
    for (int k = 0; k < 128; k++)
        acc = fmaf(redS[0][kbase + k], wout[(size_t)(kbase + k) * EMBED + col], acc);
    if (kh == 1) pS[col] = acc;
    __syncthreads();
    if (kh == 0)
        out[(size_t)a * EMBED + col] = acc + pS[col] + bout[col] + inst[(size_t)a * EMBED + col];
}

extern "C" void kernel_launch(void* const* d_in, const int* in_sizes, int n_in,
                              void* d_out, int out_size, void* d_ws, size_t ws_size,
                              hipStream_t stream) {
    const float* inst = (const float*)d_in[0];
    const float* anch = (const float*)d_in[1];
    const float* kp   = (const float*)d_in[2];
    const float* fm0  = (const float*)d_in[3];
    const float* fm1  = (const float*)d_in[4];
    const float* fm2  = (const float*)d_in[5];
    const float* fm3  = (const float*)d_in[6];
    const float* proj = (const float*)d_in[7];
    const float* wlin = (const float*)d_in[9];
    const float* blin = (const float*)d_in[10];
    const float* wout = (const float*)d_in[11];
    const float* bout = (const float*)d_in[12];
    float* out = (float*)d_out;

    char* ws = (char*)d_ws;
    size_t off = 0;
    auto alloc = [&](size_t bytes) -> void* {
        void* p = ws + off;
        off = (off + bytes + 255) & ~(size_t)255;
        return p;
    };
    __half* t0 = (__half*)alloc((size_t)NCAM * 11264 * EMBED * 2);
    __half* t1 = (__half*)alloc((size_t)NCAM * 2816 * EMBED * 2);
    __half* t2 = (__half*)alloc((size_t)NCAM * 704 * EMBED * 2);
    __half* t3 = (__half*)alloc((size_t)NCAM * 176 * EMBED * 2);
    __hip_bfloat16* wt    = (__hip_bfloat16*)alloc((size_t)NWCOL * EMBED * 2);
    __hip_bfloat16* featB = (__hip_bfloat16*)alloc((size_t)MPAD * EMBED * 2);
    float* logits = (float*)alloc((size_t)NANC * NWCOL * 4);
    float* pxy    = (float*)alloc((size_t)NANC * NCAM * NPT * 2 * 4);

    k_prep<<<dim3(2067), 256, 0, stream>>>(fm0, fm1, fm2, fm3, t0, t1, t2, t3,
                                           wlin, wt, inst, anch, featB, kp, proj, pxy);
    k_gemm<<<dim3((MT * NT + 3) / 4), 256, 0, stream>>>(featB, wt, blin, logits);
    k_aggregate<<<dim3(NANC), 512, 0, stream>>>(t0, t1, t2, t3, logits, pxy,
                                                wout, bout, inst, out);
}

// Round 6
// 217.111 us; speedup vs baseline: 1.5716x; 1.0204x over previous
//
#include <hip/hip_runtime.h>
#include <hip/hip_bf16.h>
#include <hip/hip_fp16.h>
#include <cstdint>

#define EMBED 256
#define GPS 8        // groups
#define NCAM 6
#define NLVL 4
#define NPT 13
#define NANC 900
#define NSAMP (NCAM*NLVL*NPT)   // 312
#define NWCOL (GPS*NSAMP)       // 2496
#define MPAD 928                // 29 tiles of 32 rows
#define WSTRIDE 328             // LDS stride for [g][s] weights (conflict-free)
#define MAXENT 320              // 312 rounded up to multiple of 16

// contiguous feature buffer: element base offsets per level
#define FMOFF0 0
#define FMOFF1 17301504            // 6*11264*256
#define FMOFF2 21626880            // +6*2816*256
#define FMOFF3 22708224            // +6*704*256
#define TALL_ELEMS 22978560        // +6*176*256

typedef __attribute__((ext_vector_type(8))) short bf16x8;
typedef __attribute__((ext_vector_type(16))) float f32x16;
typedef __attribute__((ext_vector_type(8))) unsigned short ushort8_t;

__device__ __forceinline__ ushort bf16bits(float x) {
    __hip_bfloat16 h = __float2bfloat16(x);
    return *reinterpret_cast<ushort*>(&h);
}
__device__ __forceinline__ ushort h16bits(float x) {
    __half h = __float2half(x);
    return *reinterpret_cast<ushort*>(&h);
}
__device__ __forceinline__ __half2 u2h2(unsigned u) {
    union { unsigned u; __half2 h; } cv; cv.u = u; return cv.h;
}

// ---------------- K1: fused prep (unchanged structure) -----------------------
__global__ __launch_bounds__(256) void k_prep(
        const float* __restrict__ fm0, const float* __restrict__ fm1,
        const float* __restrict__ fm2, const float* __restrict__ fm3,
        __half* __restrict__ t0, __half* __restrict__ t1,
        __half* __restrict__ t2, __half* __restrict__ t3,
        const float* __restrict__ wlin, __hip_bfloat16* __restrict__ wt,
        const float* __restrict__ inst, const float* __restrict__ anch,
        __hip_bfloat16* __restrict__ featB,
        const float* __restrict__ kp, const float* __restrict__ proj,
        float* __restrict__ pxy) {
    __shared__ ushort lds2[256 * 64];     // 32 KiB, shared by both transposes
    int b = blockIdx.x;
    int t = threadIdx.x;
    if (b < 1404) {
        const float* in; __half* outp; int HW, chunks, lb;
        if (b < 1056)      { in = fm0; outp = t0; HW = 11264; chunks = 176; lb = b; }
        else if (b < 1320) { in = fm1; outp = t1; HW = 2816;  chunks = 44;  lb = b - 1056; }
        else if (b < 1386) { in = fm2; outp = t2; HW = 704;   chunks = 11;  lb = b - 1320; }
        else               { in = fm3; outp = t3; HW = 176;   chunks = 3;   lb = b - 1386; }
        int c = lb / chunks;
        int hw0 = (lb - c * chunks) * 64;
        int q = t & 15, eg = t >> 4;
        bool vld = (hw0 + q * 4 + 3) < HW;
        const float* srcq = in + (size_t)c * EMBED * HW + hw0 + q * 4;
        float4 vals[16];
        #pragma unroll
        for (int r = 0; r < 16; r++) {
            int e = eg + r * 16;
            vals[r] = vld ? *(const float4*)(srcq + (size_t)e * HW)
                          : make_float4(0.f, 0.f, 0.f, 0.f);
        }
        #pragma unroll
        for (int r = 0; r < 16; r++) {
            int e = eg + r * 16;
            int sw = ((e >> 3) & 15) * 4;
            ushort4 u;
            u.x = h16bits(vals[r].x); u.y = h16bits(vals[r].y);
            u.z = h16bits(vals[r].z); u.w = h16bits(vals[r].w);
            *reinterpret_cast<ushort4*>(&lds2[e * 64 + ((q * 4) ^ sw)]) = u;
        }
        __syncthreads();
        ushort* outb = reinterpret_cast<ushort*>(outp) + ((size_t)c * HW + hw0) * EMBED;
        #pragma unroll
        for (int r = 0; r < 8; r++) {
            int flat = r * 2048 + t * 8;
            int hw = flat >> 8;
            int e0 = flat & 255;
            if (hw0 + hw < HW) {
                ushort8_t u;
                #pragma unroll
                for (int j = 0; j < 8; j++) {
                    int e = e0 + j;
                    int sw = ((e >> 3) & 15) * 4;
                    u[j] = lds2[e * 64 + (hw ^ sw)];
                }
                *reinterpret_cast<ushort8_t*>(outb + flat) = u;
            }
        }
    } else if (b < 1560) {
        int b1 = b - 1404;
        int kt = b1 / 39, nt = b1 - kt * 39;
        int k0 = kt * 64, n0 = nt * 64;
        int grp = t >> 6, nn = t & 63;
        #pragma unroll
        for (int r = 0; r < 16; r++) {
            int kk = grp * 16 + r;
            lds2[kk * 65 + nn] = bf16bits(wlin[(size_t)(k0 + kk) * NWCOL + n0 + nn]);
        }
        __syncthreads();
        ushort* wtb = reinterpret_cast<ushort*>(wt);
        int kk2 = t & 63;
        #pragma unroll
        for (int r = 0; r < 16; r++) {
            int nn2 = grp * 16 + r;
            wtb[(size_t)(n0 + nn2) * EMBED + k0 + kk2] = lds2[kk2 * 65 + nn2];
        }
    } else if (b < 1785) {
        int base = (b - 1560) * 1024 + t * 4;
        float4 a = *(const float4*)&inst[base];
        float4 c = *(const float4*)&anch[base];
        ushort4 r;
        r.x = bf16bits(a.x + c.x); r.y = bf16bits(a.y + c.y);
        r.z = bf16bits(a.z + c.z); r.w = bf16bits(a.w + c.w);
        *reinterpret_cast<ushort4*>(reinterpret_cast<ushort*>(featB) + base) = r;
    } else if (b < 1792) {
        int base = 900 * EMBED + (b - 1785) * 1024 + t * 4;
        ushort4 z; z.x = z.y = z.z = z.w = 0;
        *reinterpret_cast<ushort4*>(reinterpret_cast<ushort*>(featB) + base) = z;
    } else {
        int i = (b - 1792) * 256 + t;
        if (i < NANC * NCAM * NPT) {
            int a = i / (NCAM * NPT);
            int r = i - a * (NCAM * NPT);
            int c = r / NPT;
            int p = r - c * NPT;
            const float* M = proj + c * 16;
            const float* k3 = kp + ((size_t)a * NPT + p) * 3;
            float kx = k3[0], ky = k3[1], kz = k3[2];
            float X = M[0] * kx + M[1] * ky + M[2] * kz + M[3];
            float Y = M[4] * kx + M[5] * ky + M[6] * kz + M[7];
            float Z = M[8] * kx + M[9] * ky + M[10] * kz + M[11];
            float invz = 1.f / fmaxf(Z, 1e-5f);
            pxy[(size_t)i * 2 + 0] = X * invz;
            pxy[(size_t)i * 2 + 1] = Y * invz;
        }
    }
}

// ---------------- K2: logits GEMM via MFMA bf16 ------------------------------
#define MT 29
#define NT 78
__global__ __launch_bounds__(256) void k_gemm(const __hip_bfloat16* __restrict__ featB,
                                              const __hip_bfloat16* __restrict__ wt,
                                              const float* __restrict__ blin,
                                              float* __restrict__ logits) {
    int wv = threadIdx.x >> 6, lane = threadIdx.x & 63;
    int idx = blockIdx.x * 4 + wv;
    if (idx >= MT * NT) return;
    int mt = idx % MT, nt = idx / MT;
    int m0 = mt * 32, n0 = nt * 32;
    int l31 = lane & 31;
    int khalf = (lane >> 5) * 8;
    const short* ap = reinterpret_cast<const short*>(featB) + (size_t)(m0 + l31) * EMBED + khalf;
    const short* bp = reinterpret_cast<const short*>(wt)    + (size_t)(n0 + l31) * EMBED + khalf;
    f32x16 acc = {};
    #pragma unroll 8
    for (int ki = 0; ki < 16; ki++) {
        bf16x8 a = *reinterpret_cast<const bf16x8*>(ap + ki * 16);
        bf16x8 bb = *reinterpret_cast<const bf16x8*>(bp + ki * 16);
        acc = __builtin_amdgcn_mfma_f32_32x32x16_bf16(a, bb, acc, 0, 0, 0);
    }
    float bias = blin[n0 + l31];
    int colg = n0 + l31;
    #pragma unroll
    for (int r = 0; r < 16; r++) {
        int row = (r & 3) + 8 * (r >> 2) + 4 * (lane >> 5);
        int grow = m0 + row;
        if (grow < NANC)
            logits[(size_t)grow * NWCOL + colg] = acc[r] + bias;
    }
}

// ---------------- K3: softmax + compacted gather + fusion + out-proj ---------
// 512 threads = 8 waves. Phase A: softmax + per-sample precompute (1 thread
// per sample: validity, 4 corner offsets, corner weights) compacted into an
// LDS list (ballot + popc prefix + LDS atomic per wave), null-padded to x16.
// Phase B: waves walk the list with a 2-entry rotating register pipeline so
// 8 gather loads stay in flight (vmcnt(4) instead of full drains).
__global__ __launch_bounds__(512) void k_aggregate(const __half* __restrict__ tAll,
                                                   const float* __restrict__ logits,
                                                   const float* __restrict__ pxy,
                                                   const float* __restrict__ wout,
                                                   const float* __restrict__ bout,
                                                   const float* __restrict__ inst,
                                                   float* __restrict__ out) {
    __shared__ float wT[GPS * WSTRIDE];    // 10496 B
    __shared__ float xyS[NCAM * NPT * 2];  // 624 B
    __shared__ float redS[8][EMBED];       // 8192 B
    __shared__ float pS[EMBED];            // 1024 B
    __shared__ int4  eOff[MAXENT];         // 5120 B
    __shared__ float4 eW[MAXENT];          // 5120 B
    __shared__ int   eS[MAXENT];           // 1280 B
    __shared__ int   cntS;
    int a = blockIdx.x;
    int tid = threadIdx.x;
    int wave = tid >> 6;
    int lane = tid & 63;
    if (tid == 0) cntS = 0;
    for (int j = tid; j < NWCOL; j += 512)
        wT[(j & 7) * WSTRIDE + (j >> 3)] = logits[(size_t)a * NWCOL + j];
    for (int j = tid; j < NCAM * NPT * 2; j += 512)
        xyS[j] = pxy[(size_t)a * NCAM * NPT * 2 + j];
    __syncthreads();
    // ---- softmax: wave g owns group g ----
    {
        int g = wave;
        float m = -1e30f;
        for (int s = lane; s < NSAMP; s += 64) m = fmaxf(m, wT[g * WSTRIDE + s]);
        #pragma unroll
        for (int off = 32; off; off >>= 1) m = fmaxf(m, __shfl_xor(m, off));
        float ssum = 0.f;
        for (int s = lane; s < NSAMP; s += 64) ssum += __expf(wT[g * WSTRIDE + s] - m);
        #pragma unroll
        for (int off = 32; off; off >>= 1) ssum += __shfl_xor(ssum, off);
        float rs = 1.f / ssum;
        for (int s = lane; s < NSAMP; s += 64)
            wT[g * WSTRIDE + s] = __expf(wT[g * WSTRIDE + s] - m) * rs;
    }
    // ---- sample precompute + compaction (threads 0..311, 1 per sample) ----
    {
        bool valid = false; int4 o4; float4 w4;
        if (tid < NSAMP) {
            int c = tid / 52, rem = tid - c * 52;
            int l = rem / 13, p = rem - l * 13;
            float X = xyS[(c * NPT + p) * 2], Y = xyS[(c * NPT + p) * 2 + 1];
            int Wl = 176 >> l, Hl = 64 >> l;
            float scale = 0.25f / (float)(1 << l);
            float gx = fmaf(X, scale, -0.5f);
            float gy = fmaf(Y, scale, -0.5f);
            float x0f = floorf(gx), y0f = floorf(gy);
            float fx = gx - x0f, fy = gy - y0f;
            int x0 = (int)x0f, y0 = (int)y0f;
            int x1 = x0 + 1, y1 = y0 + 1;
            bool vx0 = (x0 >= 0) && (x0 < Wl);
            bool vx1 = (x1 >= 0) && (x1 < Wl);
            bool vy0 = (y0 >= 0) && (y0 < Hl);
            bool vy1 = (y1 >= 0) && (y1 < Hl);
            w4.x = (vx0 && vy0) ? (1.f - fx) * (1.f - fy) : 0.f;
            w4.y = (vx1 && vy0) ? fx * (1.f - fy) : 0.f;
            w4.z = (vx0 && vy1) ? (1.f - fx) * fy : 0.f;
            w4.w = (vx1 && vy1) ? fx * fy : 0.f;
            if (w4.x + w4.y + w4.z + w4.w > 0.f) {
                valid = true;
                int xc0 = min(max(x0, 0), Wl - 1), xc1 = min(max(x1, 0), Wl - 1);
                int yc0 = min(max(y0, 0), Hl - 1), yc1 = min(max(y1, 0), Hl - 1);
                const int lvlBase[4] = { FMOFF0, FMOFF1, FMOFF2, FMOFF3 };
                int cb = lvlBase[l] + c * (Wl * Hl) * EMBED;
                o4.x = cb + (yc0 * Wl + xc0) * EMBED;
                o4.y = cb + (yc0 * Wl + xc1) * EMBED;
                o4.z = cb + (yc1 * Wl + xc0) * EMBED;
                o4.w = cb + (yc1 * Wl + xc1) * EMBED;
            }
        }
        unsigned long long mask = __ballot(valid);
        int prefix = __popcll(mask & ((1ull << lane) - 1ull));
        int wcount = __popcll(mask);
        int basev = 0;
        if (lane == 0 && wcount) basev = atomicAdd(&cntS, wcount);
        basev = __shfl(basev, 0);
        if (valid) {
            int pos = basev + prefix;
            eOff[pos] = o4; eW[pos] = w4; eS[pos] = tid;
        }
    }
    __syncthreads();
    int cnt = cntS;
    int cnt_pad = (cnt + 15) & ~15;
    for (int j = cnt + tid; j < cnt_pad; j += 512) {
        eOff[j] = make_int4(0, 0, 0, 0);
        eW[j] = make_float4(0.f, 0.f, 0.f, 0.f);
        eS[j] = 0;
    }
    __syncthreads();
    // ---- phase B: pipelined gather ----
    int e0 = lane * 4;
    int g = lane >> 3;
    float a0 = 0.f, a1 = 0.f, a2 = 0.f, a3 = 0.f;
    auto consume = [&](const float4& w, int sIdx,
                       uint2 l0, uint2 l1, uint2 l2, uint2 l3) {
        float wg = wT[g * WSTRIDE + sIdx];
        __half2 W00 = __float2half2_rn(w.x), W01 = __float2half2_rn(w.y);
        __half2 W10 = __float2half2_rn(w.z), W11 = __float2half2_rn(w.w);
        __half2 blo = __hfma2(u2h2(l0.x), W00,
                      __hfma2(u2h2(l1.x), W01,
                      __hfma2(u2h2(l2.x), W10,
                      __hmul2(u2h2(l3.x), W11))));
        __half2 bhi = __hfma2(u2h2(l0.y), W00,
                      __hfma2(u2h2(l1.y), W01,
                      __hfma2(u2h2(l2.y), W10,
                      __hmul2(u2h2(l3.y), W11))));
        float2 flo = __half22float2(blo);
        float2 fhi = __half22float2(bhi);
        a0 = fmaf(wg, flo.x, a0);
        a1 = fmaf(wg, flo.y, a1);
        a2 = fmaf(wg, fhi.x, a2);
        a3 = fmaf(wg, fhi.y, a3);
    };
    int per = cnt_pad >> 3;                 // entries per wave (even)
    if (per > 0) {
        int idx = wave;
        int4 oA = eOff[idx]; float4 wA = eW[idx]; int sA = eS[idx];
        uint2 vA0 = *(const uint2*)(tAll + oA.x + e0);
        uint2 vA1 = *(const uint2*)(tAll + oA.y + e0);
        uint2 vA2 = *(const uint2*)(tAll + oA.z + e0);
        uint2 vA3 = *(const uint2*)(tAll + oA.w + e0);
        for (int it = 0; it < per; it += 2) {
            int j = idx + 8;
            int4 oB = eOff[j]; float4 wB = eW[j]; int sB = eS[j];
            uint2 vB0 = *(const uint2*)(tAll + oB.x + e0);
            uint2 vB1 = *(const uint2*)(tAll + oB.y + e0);
            uint2 vB2 = *(const uint2*)(tAll + oB.z + e0);
            uint2 vB3 = *(const uint2*)(tAll + oB.w + e0);
            consume(wA, sA, vA0, vA1, vA2, vA3);
            idx = j + 8;
            if (it + 2 < per) {
                oA = eOff[idx]; wA = eW[idx]; sA = eS[idx];
                vA0 = *(const uint2*)(tAll + oA.x + e0);
                vA1 = *(const uint2*)(tAll + oA.y + e0);
                vA2 = *(const uint2*)(tAll + oA.z + e0);
                vA3 = *(const uint2*)(tAll + oA.w + e0);
            }
            consume(wB, sB, vB0, vB1, vB2, vB3);
        }
    }
    redS[wave][e0 + 0] = a0; redS[wave][e0 + 1] = a1;
    redS[wave][e0 + 2] = a2; redS[wave][e0 + 3] = a3;
    __syncthreads();
    // ---- epilogue: fused @ w_out + b_out + inst ----
    int col = tid & 255;
    int kh = tid >> 8;
    if (kh == 0) {
        float s = redS[0][col] + redS[1][col] + redS[2][col] + redS[3][col]
                + redS[4][col] + redS[5][col] + redS[6][col] + redS[7][col];
        redS[0][col] = s;
    }
    __syncthreads();
    float acc = 0.f;
    int kbase = kh * 128;
    #pragma unroll 8
    for (int k = 0; k < 128; k++)
        acc = fmaf(redS[0][kbase + k], wout[(size_t)(kbase + k) * EMBED + col], acc);
    if (kh == 1) pS[col] = acc;
    __syncthreads();
    if (kh == 0)
        out[(size_t)a * EMBED + col] = acc + pS[col] + bout[col] + inst[(size_t)a * EMBED + col];
}

extern "C" void kernel_launch(void* const* d_in, const int* in_sizes, int n_in,
                              void* d_out, int out_size, void* d_ws, size_t ws_size,
                              hipStream_t stream) {
    const float* inst = (const float*)d_in[0];
    const float* anch = (const float*)d_in[1];
    const float* kp   = (const float*)d_in[2];
    const float* fm0  = (const float*)d_in[3];
    const float* fm1  = (const float*)d_in[4];
    const float* fm2  = (const float*)d_in[5];
    const float* fm3  = (const float*)d_in[6];
    const float* proj = (const float*)d_in[7];
    const float* wlin = (const float*)d_in[9];
    const float* blin = (const float*)d_in[10];
    const float* wout = (const float*)d_in[11];
    const float* bout = (const float*)d_in[12];
    float* out = (float*)d_out;

    char* ws = (char*)d_ws;
    size_t off = 0;
    auto alloc = [&](size_t bytes) -> void* {
        void* p = ws + off;
        off = (off + bytes + 255) & ~(size_t)255;
        return p;
    };
    __half* tAll = (__half*)alloc((size_t)TALL_ELEMS * 2);
    __half* t0 = tAll + FMOFF0;
    __half* t1 = tAll + FMOFF1;
    __half* t2 = tAll + FMOFF2;
    __half* t3 = tAll + FMOFF3;
    __hip_bfloat16* wt    = (__hip_bfloat16*)alloc((size_t)NWCOL * EMBED * 2);
    __hip_bfloat16* featB = (__hip_bfloat16*)alloc((size_t)MPAD * EMBED * 2);
    float* logits = (float*)alloc((size_t)NANC * NWCOL * 4);
    float* pxy    = (float*)alloc((size_t)NANC * NCAM * NPT * 2 * 4);

    k_prep<<<dim3(2067), 256, 0, stream>>>(fm0, fm1, fm2, fm3, t0, t1, t2, t3,
                                           wlin, wt, inst, anch, featB, kp, proj, pxy);
    k_gemm<<<dim3((MT * NT + 3) / 4), 256, 0, stream>>>(featB, wt, blin, logits);
    k_aggregate<<<dim3(NANC), 512, 0, stream>>>(tAll, logits, pxy,
                                                wout, bout, inst, out);
}